// Round 5
// baseline (190.903 us; speedup 1.0000x reference)
//
#include <hip/hip_runtime.h>

#define CHN 512
#define CKD 64
#define NPOS 4096
#define MPOS 1024

typedef __attribute__((ext_vector_type(8))) short bf16x8;
typedef __attribute__((ext_vector_type(4))) float f32x4;
typedef __attribute__((ext_vector_type(8))) unsigned short u16x8;

// workspace offsets (float units)
static constexpr size_t OFF_O   = 0;          // bf16 o [16][4096][64] (n-major, ck-minor)
static constexpr size_t OFF_THT = 4194304;    // bf16 thetaT [16][4096][64]
static constexpr size_t OFF_PHT = 6291456;    // bf16 phiT   [16][1024][64]
static constexpr size_t OFF_GB  = 6815744;    // bf16 g      [16][64][1024]
static constexpr size_t OFF_WBF = 7340032;    // bf16 W[3][64][512] (k-minor, natural)
static constexpr size_t OFF_WOB = 7389184;    // bf16 Wo [512][64] (k-minor, natural)

__device__ __forceinline__ unsigned short f2bf(float f) {
  union { float f; unsigned int u; } v; v.f = f;
  unsigned int r = v.u + 0x7FFFu + ((v.u >> 16) & 1u);
  return (unsigned short)(r >> 16);
}

__device__ __forceinline__ void gl2lds16(const void* g, void* l) {
  __builtin_amdgcn_global_load_lds(
      (const __attribute__((address_space(1))) unsigned int*)g,
      (__attribute__((address_space(3))) unsigned int*)l, 16, 0, 0);
}

// ---------------------------------------------------------------------------
// K0: weight prep. Wt/Wp/Wg fp32 [64][512] -> bf16 [3][64][512];
// Wo fp32 [512][64] -> bf16 [512][64] (both already k-minor for MFMA B).
// ---------------------------------------------------------------------------
__global__ __launch_bounds__(256) void prep_w_kernel(
    const float* __restrict__ Wt, const float* __restrict__ Wp,
    const float* __restrict__ Wg, const float* __restrict__ Wo,
    unsigned short* __restrict__ wbf, unsigned short* __restrict__ wobf)
{
  int id = blockIdx.x * 256 + threadIdx.x;   // 0..131071
  if (id < 98304) {
    int mat = id >> 15, r = id & 32767;
    const float* W = (mat == 0) ? Wt : (mat == 1) ? Wp : Wg;
    wbf[id] = f2bf(W[r]);
  } else {
    int j = id - 98304;                      // 0..32767
    wobf[j] = f2bf(Wo[j]);
  }
}

// ---------------------------------------------------------------------------
// K1a: transpose+convert x [b][512 c][4096 n] fp32 -> xT [b][4096 n][512 c] bf16.
// ---------------------------------------------------------------------------
__global__ __launch_bounds__(256) void transpose_x_kernel(
    const float* __restrict__ x, unsigned short* __restrict__ xT)
{
  __shared__ unsigned short sT[64 * 68];     // pad 4 ushorts
  const int nt = blockIdx.x, b = blockIdx.y, t = threadIdx.x;
  const int n0 = nt * 64;

  for (int c0 = 0; c0 < CHN; c0 += 64) {
    if (c0) __syncthreads();
#pragma unroll
    for (int i = 0; i < 4; ++i) {
      int idx = i * 256 + t;                 // 0..1023 float4
      int cc = idx >> 4, f4 = idx & 15;
      float4 v = *(const float4*)(x + ((size_t)b * CHN + c0 + cc) * NPOS + n0 + f4 * 4);
      ushort4 u;
      u.x = f2bf(v.x); u.y = f2bf(v.y); u.z = f2bf(v.z); u.w = f2bf(v.w);
      *(ushort4*)&sT[cc * 68 + f4 * 4] = u;
    }
    __syncthreads();
#pragma unroll
    for (int i = 0; i < 2; ++i) {
      int idx = i * 256 + t;                 // 0..511
      int nn = idx >> 3, co = idx & 7;
      u16x8 u;
#pragma unroll
      for (int e = 0; e < 8; ++e) u[e] = sT[(co * 8 + e) * 68 + nn];
      *(u16x8*)(xT + ((size_t)b * NPOS + n0 + nn) * CHN + c0 + co * 8) = u;
    }
  }
}

// ---------------------------------------------------------------------------
// K1b: qkv GEMM via MFMA. (unchanged from round 4)
// ---------------------------------------------------------------------------
__global__ __launch_bounds__(256) void qkv_mfma_kernel(
    const unsigned short* __restrict__ xT,   // [b][4096][512]
    const unsigned short* __restrict__ wbf,  // [3][64][512]
    unsigned short* __restrict__ thT, unsigned short* __restrict__ phT,
    unsigned short* __restrict__ gbf)
{
  __shared__ unsigned short sX[128 * 64];    // [rn][c] rows 128B, swizzled content
  __shared__ unsigned short sW[3 * 64 * 64]; // [mat][ck][c] rows 128B, swizzled

  const int bx = blockIdx.x;
  const int b  = blockIdx.y;
  const int t  = threadIdx.x;
  const int w   = t >> 6;
  const int l   = t & 63;
  const int l16 = l & 15;
  const int lhi = l >> 4;
  const int n0  = bx * 128;

  f32x4 acc[3][2][4];
#pragma unroll
  for (int m = 0; m < 3; ++m)
#pragma unroll
    for (int nf = 0; nf < 2; ++nf)
#pragma unroll
      for (int ckf = 0; ckf < 4; ++ckf) acc[m][nf][ckf] = (f32x4){0.f, 0.f, 0.f, 0.f};

  for (int c0 = 0; c0 < CHN; c0 += 64) {
    if (c0) __syncthreads();
#pragma unroll
    for (int i = 0; i < 4; ++i) {
      int row = (i * 4 + w) * 8 + (l >> 3);  // 0..127
      int sbyte = (l & 7) * 16;
      const char* g = (const char*)xT +
          ((((size_t)b * NPOS + n0 + row) * CHN + c0) << 1) + (sbyte ^ ((row & 7) << 4));
      gl2lds16(g, (char*)sX + (i * 4 + w) * 1024);
    }
#pragma unroll
    for (int mi = 0; mi < 6; ++mi) {
      int mat = mi >> 1;
      int row = ((mi & 1) * 4 + w) * 8 + (l >> 3);   // 0..63
      int sbyte = (l & 7) * 16;
      const char* g = (const char*)wbf +
          ((((size_t)mat * 64 + row) * CHN + c0) << 1) + (sbyte ^ ((row & 7) << 4));
      gl2lds16(g, (char*)sW + mi * 4096 + w * 1024);
    }
    __syncthreads();

#pragma unroll
    for (int ks = 0; ks < 2; ++ks) {
      const int cu = ks * 32 + lhi * 8;      // ushort col
      bf16x8 a[2];
#pragma unroll
      for (int nf = 0; nf < 2; ++nf) {
        int rn = 16 * w + 64 * nf + l16;
        a[nf] = *(const bf16x8*)&sX[rn * 64 + (cu ^ ((rn & 7) * 8))];
      }
#pragma unroll
      for (int m = 0; m < 3; ++m)
#pragma unroll
        for (int ckf = 0; ckf < 4; ++ckf) {
          int rw = ckf * 16 + l16;
          bf16x8 bb = *(const bf16x8*)&sW[m * 4096 + rw * 64 + (cu ^ ((rw & 7) * 8))];
          acc[m][0][ckf] = __builtin_amdgcn_mfma_f32_16x16x32_bf16(a[0], bb, acc[m][0][ckf], 0, 0, 0);
          acc[m][1][ckf] = __builtin_amdgcn_mfma_f32_16x16x32_bf16(a[1], bb, acc[m][1][ckf], 0, 0, 0);
        }
    }
  }

  unsigned short* th = thT + (size_t)b * NPOS * 64;
#pragma unroll
  for (int nf = 0; nf < 2; ++nf)
#pragma unroll
    for (int r = 0; r < 4; ++r) {
      int n = n0 + 16 * w + 64 * nf + lhi * 4 + r;
#pragma unroll
      for (int ckf = 0; ckf < 4; ++ckf)
        th[(size_t)n * 64 + ckf * 16 + l16] = f2bf(acc[0][nf][ckf][r]);
    }

  unsigned short* ph = phT + (size_t)b * MPOS * 64;
  unsigned short* gb = gbf + (size_t)b * CKD * MPOS;
#pragma unroll
  for (int pr = 0; pr < 2; ++pr) {
    int mcol = bx * 32 + 8 * w + lhi * 2 + pr;
#pragma unroll
    for (int ckf = 0; ckf < 4; ++ckf) {
      int ck = ckf * 16 + l16;
      float vp = fmaxf(fmaxf(acc[1][0][ckf][2 * pr], acc[1][0][ckf][2 * pr + 1]),
                       fmaxf(acc[1][1][ckf][2 * pr], acc[1][1][ckf][2 * pr + 1]));
      float vg = fmaxf(fmaxf(acc[2][0][ckf][2 * pr], acc[2][0][ckf][2 * pr + 1]),
                       fmaxf(acc[2][1][ckf][2 * pr], acc[2][1][ckf][2 * pr + 1]));
      ph[(size_t)mcol * 64 + ck] = f2bf(vp);
      gb[(size_t)ck * MPOS + mcol] = f2bf(vg);
    }
  }
}

// ---------------------------------------------------------------------------
// K2: fused flash attention. Epilogue now writes o as bf16 [b][n][64ck]
// (k-minor A-operand layout for the MFMA outconv).
// ---------------------------------------------------------------------------
__global__ __launch_bounds__(256) void attn_kernel(
    const unsigned short* __restrict__ thT,  // [b][4096][64]
    const unsigned short* __restrict__ phT,  // [b][1024][64]
    const unsigned short* __restrict__ gbf,  // [b][64][1024]
    unsigned short* __restrict__ obf)        // [b][4096][64] bf16
{
  __shared__ unsigned short sTh[64 * 64];
  __shared__ unsigned short sPhi[64 * 64];
  __shared__ unsigned short sG[64 * 64];
  __shared__ unsigned short sP[64 * 64];

  const int qt = blockIdx.x;
  const int b  = blockIdx.y;
  const int t  = threadIdx.x;
  const int w   = t >> 6;
  const int l   = t & 63;
  const int l16 = l & 15;
  const int lhi = l >> 4;

  {
    const unsigned short* src = thT + ((size_t)b * NPOS + (size_t)qt * 64) * 64;
#pragma unroll
    for (int c = t; c < 512; c += 256) {
      int row = c >> 3, c8 = c & 7;
      *(f32x4*)&sTh[row * 64 + ((c8 * 8) ^ ((row & 7) * 8))] =
          *(const f32x4*)(src + row * 64 + c8 * 8);
    }
  }

  f32x4 oacc[4];
  float m_run[4], l_run[4];
#pragma unroll
  for (int i = 0; i < 4; ++i) {
    oacc[i] = (f32x4){0.f, 0.f, 0.f, 0.f};
    m_run[i] = -1e30f; l_run[i] = 0.f;
  }

  const unsigned short* phb = phT + (size_t)b * MPOS * 64;
  const unsigned short* gb  = gbf + (size_t)b * CKD * MPOS;

  for (int mt = 0; mt < 16; ++mt) {
    __syncthreads();
#pragma unroll
    for (int c = t; c < 512; c += 256) {
      int row = c >> 3, c8 = c & 7;
      *(f32x4*)&sPhi[row * 64 + ((c8 * 8) ^ ((row & 7) * 8))] =
          *(const f32x4*)(phb + (size_t)(mt * 64 + row) * 64 + c8 * 8);
    }
#pragma unroll
    for (int c = t; c < 512; c += 256) {
      int row = c >> 3, c8 = c & 7;
      *(f32x4*)&sG[row * 64 + ((c8 * 8) ^ ((row & 7) * 8))] =
          *(const f32x4*)(gb + (size_t)row * MPOS + mt * 64 + c8 * 8);
    }
    __syncthreads();

    f32x4 sacc[4];
#pragma unroll
    for (int mf = 0; mf < 4; ++mf) sacc[mf] = (f32x4){0.f, 0.f, 0.f, 0.f};
#pragma unroll
    for (int ks = 0; ks < 2; ++ks) {
      const int q  = 16 * w + l16;
      const int ob = lhi * 8 + 32 * ks;
      bf16x8 a = *(const bf16x8*)&sTh[q * 64 + (ob ^ ((q & 7) * 8))];
#pragma unroll
      for (int mf = 0; mf < 4; ++mf) {
        const int m = l16 + 16 * mf;
        bf16x8 bb = *(const bf16x8*)&sPhi[m * 64 + (ob ^ ((m & 7) * 8))];
        sacc[mf] = __builtin_amdgcn_mfma_f32_16x16x32_bf16(a, bb, sacc[mf], 0, 0, 0);
      }
    }

    float sc[4];
#pragma unroll
    for (int r = 0; r < 4; ++r) {
      float mx = fmaxf(fmaxf(sacc[0][r], sacc[1][r]), fmaxf(sacc[2][r], sacc[3][r]));
      mx = fmaxf(mx, __shfl_xor(mx, 1, 64));
      mx = fmaxf(mx, __shfl_xor(mx, 2, 64));
      mx = fmaxf(mx, __shfl_xor(mx, 4, 64));
      mx = fmaxf(mx, __shfl_xor(mx, 8, 64));
      float mnew = fmaxf(m_run[r], mx);
      sc[r] = __expf(m_run[r] - mnew);
      m_run[r] = mnew;
      float rs = 0.f;
#pragma unroll
      for (int mf = 0; mf < 4; ++mf) {
        float p = __expf(sacc[mf][r] - mnew);
        sacc[mf][r] = p;
        rs += p;
      }
      rs += __shfl_xor(rs, 1, 64);
      rs += __shfl_xor(rs, 2, 64);
      rs += __shfl_xor(rs, 4, 64);
      rs += __shfl_xor(rs, 8, 64);
      l_run[r] = l_run[r] * sc[r] + rs;
    }

#pragma unroll
    for (int r = 0; r < 4; ++r) {
      const int qq = 16 * w + lhi * 4 + r;
      const int swz = (qq & 7) * 8;
#pragma unroll
      for (int mf = 0; mf < 4; ++mf) {
        const int m = l16 + 16 * mf;
        sP[qq * 64 + ((m & 0x38) ^ swz) + (m & 7)] = f2bf(sacc[mf][r]);
      }
    }

#pragma unroll
    for (int ckf = 0; ckf < 4; ++ckf)
#pragma unroll
      for (int r = 0; r < 4; ++r) oacc[ckf][r] *= sc[r];

#pragma unroll
    for (int ks = 0; ks < 2; ++ks) {
      const int q  = 16 * w + l16;
      const int ob = lhi * 8 + 32 * ks;
      bf16x8 a = *(const bf16x8*)&sP[q * 64 + (ob ^ ((q & 7) * 8))];
#pragma unroll
      for (int ckf = 0; ckf < 4; ++ckf) {
        const int ck = l16 + 16 * ckf;
        bf16x8 bb = *(const bf16x8*)&sG[ck * 64 + (ob ^ ((ck & 7) * 8))];
        oacc[ckf] = __builtin_amdgcn_mfma_f32_16x16x32_bf16(a, bb, oacc[ckf], 0, 0, 0);
      }
    }
  }

  float inv[4];
#pragma unroll
  for (int r = 0; r < 4; ++r) inv[r] = 1.0f / l_run[r];

  // o bf16 [n][ck] epilogue (same pattern as theta write in qkv)
  unsigned short* ob = obf + (size_t)b * NPOS * 64;
#pragma unroll
  for (int r = 0; r < 4; ++r) {
    int n = qt * 64 + 16 * w + lhi * 4 + r;
#pragma unroll
    for (int ckf = 0; ckf < 4; ++ckf)
      ob[(size_t)n * 64 + ckf * 16 + l16] = f2bf(oacc[ckf][r] * inv[r]);
  }
}

// ---------------------------------------------------------------------------
// K3: out = x + gamma * (Wo @ o) via bf16 MFMA.
// grid (64 n-tiles of 64, 2 co-tiles of 256, 16 b), 256 thr = 4 waves.
// Wave w owns co range [ct*256 + 64w, +64). A = o [n][ck], B = Wo [co][ck].
// D rows = n (float4 epilogue stores along n), cols = co.
// ---------------------------------------------------------------------------
__global__ __launch_bounds__(256) void outconv_mfma_kernel(
    const float* __restrict__ x,
    const unsigned short* __restrict__ wobf,  // [512][64] bf16 k-minor
    const unsigned short* __restrict__ obf,   // [b][4096][64] bf16
    const float* __restrict__ gamma_p, float* __restrict__ outp)
{
  __shared__ unsigned short sO[64 * 64];      // [n][ck] rows 128B, swizzled
  __shared__ unsigned short sWo[256 * 64];    // [co][ck] rows 128B, swizzled

  const int nt = blockIdx.x;
  const int ct = blockIdx.y;
  const int b  = blockIdx.z;
  const int t  = threadIdx.x;
  const int w   = t >> 6;
  const int l   = t & 63;
  const int l16 = l & 15;
  const int lhi = l >> 4;

  // stage o tile: 64 rows x 128B = 512 chunks of 16B
#pragma unroll
  for (int i = 0; i < 2; ++i) {
    int cidx = i * 256 + t;                   // = i*256 + w*64 + l
    int row = cidx >> 3, sub = cidx & 7;
    const char* g = (const char*)obf +
        ((((size_t)b * NPOS + nt * 64 + row) * 64) << 1) + ((sub * 16) ^ ((row & 7) << 4));
    gl2lds16(g, (char*)sO + (i * 256 + w * 64) * 16);
  }
  // stage Wo tile: 256 rows x 128B = 2048 chunks of 16B
#pragma unroll
  for (int i = 0; i < 8; ++i) {
    int cidx = i * 256 + t;
    int row = cidx >> 3, sub = cidx & 7;      // row 0..255
    const char* g = (const char*)wobf +
        ((((size_t)(ct * 256 + row)) * 64) << 1) + ((sub * 16) ^ ((row & 7) << 4));
    gl2lds16(g, (char*)sWo + (i * 256 + w * 64) * 16);
  }
  __syncthreads();

  f32x4 acc[4][4];                            // [nf][colf]
#pragma unroll
  for (int nf = 0; nf < 4; ++nf)
#pragma unroll
    for (int cf = 0; cf < 4; ++cf) acc[nf][cf] = (f32x4){0.f, 0.f, 0.f, 0.f};

#pragma unroll
  for (int ks = 0; ks < 2; ++ks) {
    const int cu = ks * 32 + lhi * 8;
    bf16x8 a[4];
#pragma unroll
    for (int nf = 0; nf < 4; ++nf) {
      int rn = nf * 16 + l16;
      a[nf] = *(const bf16x8*)&sO[rn * 64 + (cu ^ ((rn & 7) * 8))];
    }
#pragma unroll
    for (int cf = 0; cf < 4; ++cf) {
      int rw = w * 64 + cf * 16 + l16;
      bf16x8 bb = *(const bf16x8*)&sWo[rw * 64 + (cu ^ ((rw & 7) * 8))];
#pragma unroll
      for (int nf = 0; nf < 4; ++nf)
        acc[nf][cf] = __builtin_amdgcn_mfma_f32_16x16x32_bf16(a[nf], bb, acc[nf][cf], 0, 0, 0);
    }
  }

  const float gv = *gamma_p;
#pragma unroll
  for (int nf = 0; nf < 4; ++nf) {
    const int n = nt * 64 + nf * 16 + lhi * 4;
#pragma unroll
    for (int cf = 0; cf < 4; ++cf) {
      const int co = ct * 256 + w * 64 + cf * 16 + l16;
      const size_t off = ((size_t)b * CHN + co) * NPOS + n;
      float4 xv = *(const float4*)(x + off);
      float4 rr;
      rr.x = fmaf(gv, acc[nf][cf][0], xv.x);
      rr.y = fmaf(gv, acc[nf][cf][1], xv.y);
      rr.z = fmaf(gv, acc[nf][cf][2], xv.z);
      rr.w = fmaf(gv, acc[nf][cf][3], xv.w);
      *(float4*)(outp + off) = rr;
    }
  }
}

// ---------------------------------------------------------------------------
extern "C" void kernel_launch(void* const* d_in, const int* in_sizes, int n_in,
                              void* d_out, int out_size, void* d_ws, size_t ws_size,
                              hipStream_t stream)
{
  const float* x     = (const float*)d_in[0];
  const float* Wt    = (const float*)d_in[1];
  const float* Wp    = (const float*)d_in[2];
  const float* Wg    = (const float*)d_in[3];
  const float* Wo    = (const float*)d_in[4];
  const float* gamma = (const float*)d_in[5];
  float* out = (float*)d_out;
  float* ws  = (float*)d_ws;

  unsigned short* obf = (unsigned short*)(ws + OFF_O);
  unsigned short* thT = (unsigned short*)(ws + OFF_THT);
  unsigned short* phT = (unsigned short*)(ws + OFF_PHT);
  unsigned short* gbf = (unsigned short*)(ws + OFF_GB);
  unsigned short* wbf = (unsigned short*)(ws + OFF_WBF);
  unsigned short* wob = (unsigned short*)(ws + OFF_WOB);
  // xT bf16 [16][4096][512] = 67 MB scratch in d_out's 134 MB; fully consumed
  // by qkv_mfma before outconv overwrites d_out. Rewritten every call.
  unsigned short* xT  = (unsigned short*)d_out;

  prep_w_kernel<<<dim3(512), 256, 0, stream>>>(Wt, Wp, Wg, Wo, wbf, wob);
  transpose_x_kernel<<<dim3(64, 16), 256, 0, stream>>>(x, xT);
  qkv_mfma_kernel<<<dim3(32, 16), 256, 0, stream>>>(xT, wbf, thT, phT, gbf);
  attn_kernel<<<dim3(64, 16), 256, 0, stream>>>(thT, phT, gbf, obf);
  outconv_mfma_kernel<<<dim3(64, 2, 16), 256, 0, stream>>>(x, wob, obf, gamma, out);
}

// Round 6
// 162.412 us; speedup vs baseline: 1.1754x; 1.1754x over previous
//
#include <hip/hip_runtime.h>

#define CHN 512
#define CKD 64
#define NPOS 4096
#define MPOS 1024

typedef __attribute__((ext_vector_type(8))) short bf16x8;
typedef __attribute__((ext_vector_type(4))) float f32x4;
typedef __attribute__((ext_vector_type(8))) unsigned short u16x8;

// workspace offsets (float units)
static constexpr size_t OFF_O   = 0;          // bf16 o [16][4096][64] (n-major, ck-minor)
static constexpr size_t OFF_THT = 4194304;    // bf16 thetaT [16][4096][64]
static constexpr size_t OFF_PHT = 6291456;    // bf16 phiT   [16][1024][64]
static constexpr size_t OFF_GB  = 6815744;    // bf16 g      [16][64][1024]
static constexpr size_t OFF_WBF = 7340032;    // bf16 W[3][64][512] (k-minor, natural)
static constexpr size_t OFF_WOB = 7389184;    // bf16 Wo [512][64] (k-minor, natural)

__device__ __forceinline__ unsigned short f2bf(float f) {
  union { float f; unsigned int u; } v; v.f = f;
  unsigned int r = v.u + 0x7FFFu + ((v.u >> 16) & 1u);
  return (unsigned short)(r >> 16);
}

__device__ __forceinline__ void gl2lds16(const void* g, void* l) {
  __builtin_amdgcn_global_load_lds(
      (const __attribute__((address_space(1))) unsigned int*)g,
      (__attribute__((address_space(3))) unsigned int*)l, 16, 0, 0);
}

// ---------------------------------------------------------------------------
// K0: weight prep. Wt/Wp/Wg fp32 [64][512] -> bf16 [3][64][512];
// Wo fp32 [512][64] -> bf16 [512][64] (both already k-minor for MFMA B).
// ---------------------------------------------------------------------------
__global__ __launch_bounds__(256) void prep_w_kernel(
    const float* __restrict__ Wt, const float* __restrict__ Wp,
    const float* __restrict__ Wg, const float* __restrict__ Wo,
    unsigned short* __restrict__ wbf, unsigned short* __restrict__ wobf)
{
  int id = blockIdx.x * 256 + threadIdx.x;   // 0..131071
  if (id < 98304) {
    int mat = id >> 15, r = id & 32767;
    const float* W = (mat == 0) ? Wt : (mat == 1) ? Wp : Wg;
    wbf[id] = f2bf(W[r]);
  } else {
    int j = id - 98304;                      // 0..32767
    wobf[j] = f2bf(Wo[j]);
  }
}

// ---------------------------------------------------------------------------
// K1: FUSED transpose + qkv GEMM via MFMA. Reads x [b][512c][4096n] fp32
// directly (no xT intermediate: saves 268 MB HBM traffic vs r5 pipeline).
// grid (32 n-tiles of 128, 16 b), 256 thr = 4 waves.
// x chunk staged in NATURAL [64c][128n+4pad] bf16 orientation (coalesced
// global float4 -> ushort4 LDS writes, 8B aligned). A-fragments assembled
// via 8 scalar ds_read_u16 along the c-column (2-way bank aliasing = free).
// W staged via global_load_lds(16B) swizzled-source (unchanged, proven).
// Outputs: thetaT bf16 [n][ck]; phi pooled [m][ck]; g pooled [ck][m].
// ---------------------------------------------------------------------------
__global__ __launch_bounds__(256) void qkv_fused_kernel(
    const float* __restrict__ x,             // [b][512][4096] fp32
    const unsigned short* __restrict__ wbf,  // [3][64][512]
    unsigned short* __restrict__ thT, unsigned short* __restrict__ phT,
    unsigned short* __restrict__ gbf)
{
  __shared__ unsigned short sXb[64 * 132];   // [c][n] bf16, +4 pad
  __shared__ unsigned short sW[3 * 64 * 64]; // [mat][ck][c] rows 128B, swizzled

  const int bx = blockIdx.x;
  const int b  = blockIdx.y;
  const int t  = threadIdx.x;
  const int w   = t >> 6;
  const int l   = t & 63;
  const int l16 = l & 15;
  const int lhi = l >> 4;
  const int n0  = bx * 128;

  const float* xb = x + (size_t)b * CHN * NPOS + n0;

  f32x4 acc[3][2][4];
#pragma unroll
  for (int m = 0; m < 3; ++m)
#pragma unroll
    for (int nf = 0; nf < 2; ++nf)
#pragma unroll
      for (int ckf = 0; ckf < 4; ++ckf) acc[m][nf][ckf] = (f32x4){0.f, 0.f, 0.f, 0.f};

  for (int c0 = 0; c0 < CHN; c0 += 64) {
    if (c0) __syncthreads();                 // previous chunk readers done
    // stage x chunk [64c][128n] fp32 -> bf16, natural orientation
#pragma unroll
    for (int i = 0; i < 8; ++i) {
      int row  = i * 8 + (t >> 5);           // 0..63
      int col4 = t & 31;                     // float4 index along n
      float4 v = *(const float4*)(xb + (size_t)(c0 + row) * NPOS + col4 * 4);
      ushort4 u;
      u.x = f2bf(v.x); u.y = f2bf(v.y); u.z = f2bf(v.z); u.w = f2bf(v.w);
      *(ushort4*)&sXb[row * 132 + col4 * 4] = u;
    }
    // stage W tiles: 3 x 64 rows x 128 B (async, drained by barrier)
#pragma unroll
    for (int mi = 0; mi < 6; ++mi) {
      int mat = mi >> 1;
      int row = ((mi & 1) * 4 + w) * 8 + (l >> 3);   // 0..63
      int sbyte = (l & 7) * 16;
      const char* g = (const char*)wbf +
          ((((size_t)mat * 64 + row) * CHN + c0) << 1) + (sbyte ^ ((row & 7) << 4));
      gl2lds16(g, (char*)sW + mi * 4096 + w * 1024);
    }
    __syncthreads();

#pragma unroll
    for (int ks = 0; ks < 2; ++ks) {
      const int cu = ks * 32 + lhi * 8;      // channel base of this k-slice
      bf16x8 a[2];
#pragma unroll
      for (int nf = 0; nf < 2; ++nf) {
        const int rn = 16 * w + 64 * nf + l16;
        bf16x8 av;
#pragma unroll
        for (int e = 0; e < 8; ++e)
          av[e] = (short)sXb[(cu + e) * 132 + rn];
        a[nf] = av;
      }
#pragma unroll
      for (int m = 0; m < 3; ++m)
#pragma unroll
        for (int ckf = 0; ckf < 4; ++ckf) {
          int rw = ckf * 16 + l16;
          bf16x8 bb = *(const bf16x8*)&sW[m * 4096 + rw * 64 + ((ks * 32 + lhi * 8) ^ ((rw & 7) * 8))];
          acc[m][0][ckf] = __builtin_amdgcn_mfma_f32_16x16x32_bf16(a[0], bb, acc[m][0][ckf], 0, 0, 0);
          acc[m][1][ckf] = __builtin_amdgcn_mfma_f32_16x16x32_bf16(a[1], bb, acc[m][1][ckf], 0, 0, 0);
        }
    }
  }

  // epilogue: theta full-res [n][ck] bf16
  unsigned short* th = thT + (size_t)b * NPOS * 64;
#pragma unroll
  for (int nf = 0; nf < 2; ++nf)
#pragma unroll
    for (int r = 0; r < 4; ++r) {
      int n = n0 + 16 * w + 64 * nf + lhi * 4 + r;
#pragma unroll
      for (int ckf = 0; ckf < 4; ++ckf)
        th[(size_t)n * 64 + ckf * 16 + l16] = f2bf(acc[0][nf][ckf][r]);
    }

  // phi/g: 2x2 maxpool in-register. pooled row = bx, col j = 8w + lhi*2 + pr.
  unsigned short* ph = phT + (size_t)b * MPOS * 64;
  unsigned short* gb = gbf + (size_t)b * CKD * MPOS;
#pragma unroll
  for (int pr = 0; pr < 2; ++pr) {
    int mcol = bx * 32 + 8 * w + lhi * 2 + pr;
#pragma unroll
    for (int ckf = 0; ckf < 4; ++ckf) {
      int ck = ckf * 16 + l16;
      float vp = fmaxf(fmaxf(acc[1][0][ckf][2 * pr], acc[1][0][ckf][2 * pr + 1]),
                       fmaxf(acc[1][1][ckf][2 * pr], acc[1][1][ckf][2 * pr + 1]));
      float vg = fmaxf(fmaxf(acc[2][0][ckf][2 * pr], acc[2][0][ckf][2 * pr + 1]),
                       fmaxf(acc[2][1][ckf][2 * pr], acc[2][1][ckf][2 * pr + 1]));
      ph[(size_t)mcol * 64 + ck] = f2bf(vp);
      gb[(size_t)ck * MPOS + mcol] = f2bf(vg);
    }
  }
}

// ---------------------------------------------------------------------------
// K2: fused flash attention, bf16 MFMA, fp32 accum. o -> bf16 [b][n][64ck].
// ---------------------------------------------------------------------------
__global__ __launch_bounds__(256) void attn_kernel(
    const unsigned short* __restrict__ thT,  // [b][4096][64]
    const unsigned short* __restrict__ phT,  // [b][1024][64]
    const unsigned short* __restrict__ gbf,  // [b][64][1024]
    unsigned short* __restrict__ obf)        // [b][4096][64] bf16
{
  __shared__ unsigned short sTh[64 * 64];
  __shared__ unsigned short sPhi[64 * 64];
  __shared__ unsigned short sG[64 * 64];
  __shared__ unsigned short sP[64 * 64];

  const int qt = blockIdx.x;
  const int b  = blockIdx.y;
  const int t  = threadIdx.x;
  const int w   = t >> 6;
  const int l   = t & 63;
  const int l16 = l & 15;
  const int lhi = l >> 4;

  {
    const unsigned short* src = thT + ((size_t)b * NPOS + (size_t)qt * 64) * 64;
#pragma unroll
    for (int c = t; c < 512; c += 256) {
      int row = c >> 3, c8 = c & 7;
      *(f32x4*)&sTh[row * 64 + ((c8 * 8) ^ ((row & 7) * 8))] =
          *(const f32x4*)(src + row * 64 + c8 * 8);
    }
  }

  f32x4 oacc[4];
  float m_run[4], l_run[4];
#pragma unroll
  for (int i = 0; i < 4; ++i) {
    oacc[i] = (f32x4){0.f, 0.f, 0.f, 0.f};
    m_run[i] = -1e30f; l_run[i] = 0.f;
  }

  const unsigned short* phb = phT + (size_t)b * MPOS * 64;
  const unsigned short* gb  = gbf + (size_t)b * CKD * MPOS;

  for (int mt = 0; mt < 16; ++mt) {
    __syncthreads();
#pragma unroll
    for (int c = t; c < 512; c += 256) {
      int row = c >> 3, c8 = c & 7;
      *(f32x4*)&sPhi[row * 64 + ((c8 * 8) ^ ((row & 7) * 8))] =
          *(const f32x4*)(phb + (size_t)(mt * 64 + row) * 64 + c8 * 8);
    }
#pragma unroll
    for (int c = t; c < 512; c += 256) {
      int row = c >> 3, c8 = c & 7;
      *(f32x4*)&sG[row * 64 + ((c8 * 8) ^ ((row & 7) * 8))] =
          *(const f32x4*)(gb + (size_t)row * MPOS + mt * 64 + c8 * 8);
    }
    __syncthreads();

    f32x4 sacc[4];
#pragma unroll
    for (int mf = 0; mf < 4; ++mf) sacc[mf] = (f32x4){0.f, 0.f, 0.f, 0.f};
#pragma unroll
    for (int ks = 0; ks < 2; ++ks) {
      const int q  = 16 * w + l16;
      const int ob = lhi * 8 + 32 * ks;
      bf16x8 a = *(const bf16x8*)&sTh[q * 64 + (ob ^ ((q & 7) * 8))];
#pragma unroll
      for (int mf = 0; mf < 4; ++mf) {
        const int m = l16 + 16 * mf;
        bf16x8 bb = *(const bf16x8*)&sPhi[m * 64 + (ob ^ ((m & 7) * 8))];
        sacc[mf] = __builtin_amdgcn_mfma_f32_16x16x32_bf16(a, bb, sacc[mf], 0, 0, 0);
      }
    }

    float sc[4];
#pragma unroll
    for (int r = 0; r < 4; ++r) {
      float mx = fmaxf(fmaxf(sacc[0][r], sacc[1][r]), fmaxf(sacc[2][r], sacc[3][r]));
      mx = fmaxf(mx, __shfl_xor(mx, 1, 64));
      mx = fmaxf(mx, __shfl_xor(mx, 2, 64));
      mx = fmaxf(mx, __shfl_xor(mx, 4, 64));
      mx = fmaxf(mx, __shfl_xor(mx, 8, 64));
      float mnew = fmaxf(m_run[r], mx);
      sc[r] = __expf(m_run[r] - mnew);
      m_run[r] = mnew;
      float rs = 0.f;
#pragma unroll
      for (int mf = 0; mf < 4; ++mf) {
        float p = __expf(sacc[mf][r] - mnew);
        sacc[mf][r] = p;
        rs += p;
      }
      rs += __shfl_xor(rs, 1, 64);
      rs += __shfl_xor(rs, 2, 64);
      rs += __shfl_xor(rs, 4, 64);
      rs += __shfl_xor(rs, 8, 64);
      l_run[r] = l_run[r] * sc[r] + rs;
    }

#pragma unroll
    for (int r = 0; r < 4; ++r) {
      const int qq = 16 * w + lhi * 4 + r;
      const int swz = (qq & 7) * 8;
#pragma unroll
      for (int mf = 0; mf < 4; ++mf) {
        const int m = l16 + 16 * mf;
        sP[qq * 64 + ((m & 0x38) ^ swz) + (m & 7)] = f2bf(sacc[mf][r]);
      }
    }

#pragma unroll
    for (int ckf = 0; ckf < 4; ++ckf)
#pragma unroll
      for (int r = 0; r < 4; ++r) oacc[ckf][r] *= sc[r];

#pragma unroll
    for (int ks = 0; ks < 2; ++ks) {
      const int q  = 16 * w + l16;
      const int ob = lhi * 8 + 32 * ks;
      bf16x8 a = *(const bf16x8*)&sP[q * 64 + (ob ^ ((q & 7) * 8))];
#pragma unroll
      for (int ckf = 0; ckf < 4; ++ckf) {
        const int ck = l16 + 16 * ckf;
        bf16x8 bb = *(const bf16x8*)&sG[ck * 64 + (ob ^ ((ck & 7) * 8))];
        oacc[ckf] = __builtin_amdgcn_mfma_f32_16x16x32_bf16(a, bb, oacc[ckf], 0, 0, 0);
      }
    }
  }

  float inv[4];
#pragma unroll
  for (int r = 0; r < 4; ++r) inv[r] = 1.0f / l_run[r];

  unsigned short* ob = obf + (size_t)b * NPOS * 64;
#pragma unroll
  for (int r = 0; r < 4; ++r) {
    int n = qt * 64 + 16 * w + lhi * 4 + r;
#pragma unroll
    for (int ckf = 0; ckf < 4; ++ckf)
      ob[(size_t)n * 64 + ckf * 16 + l16] = f2bf(oacc[ckf][r] * inv[r]);
  }
}

// ---------------------------------------------------------------------------
// K3: out = x + gamma * (Wo @ o) via bf16 MFMA. (unchanged from round 5)
// ---------------------------------------------------------------------------
__global__ __launch_bounds__(256) void outconv_mfma_kernel(
    const float* __restrict__ x,
    const unsigned short* __restrict__ wobf,  // [512][64] bf16 k-minor
    const unsigned short* __restrict__ obf,   // [b][4096][64] bf16
    const float* __restrict__ gamma_p, float* __restrict__ outp)
{
  __shared__ unsigned short sO[64 * 64];      // [n][ck] rows 128B, swizzled
  __shared__ unsigned short sWo[256 * 64];    // [co][ck] rows 128B, swizzled

  const int nt = blockIdx.x;
  const int ct = blockIdx.y;
  const int b  = blockIdx.z;
  const int t  = threadIdx.x;
  const int w   = t >> 6;
  const int l   = t & 63;
  const int l16 = l & 15;
  const int lhi = l >> 4;

#pragma unroll
  for (int i = 0; i < 2; ++i) {
    int cidx = i * 256 + t;
    int row = cidx >> 3, sub = cidx & 7;
    const char* g = (const char*)obf +
        ((((size_t)b * NPOS + nt * 64 + row) * 64) << 1) + ((sub * 16) ^ ((row & 7) << 4));
    gl2lds16(g, (char*)sO + (i * 256 + w * 64) * 16);
  }
#pragma unroll
  for (int i = 0; i < 8; ++i) {
    int cidx = i * 256 + t;
    int row = cidx >> 3, sub = cidx & 7;
    const char* g = (const char*)wobf +
        ((((size_t)(ct * 256 + row)) * 64) << 1) + ((sub * 16) ^ ((row & 7) << 4));
    gl2lds16(g, (char*)sWo + (i * 256 + w * 64) * 16);
  }
  __syncthreads();

  f32x4 acc[4][4];
#pragma unroll
  for (int nf = 0; nf < 4; ++nf)
#pragma unroll
    for (int cf = 0; cf < 4; ++cf) acc[nf][cf] = (f32x4){0.f, 0.f, 0.f, 0.f};

#pragma unroll
  for (int ks = 0; ks < 2; ++ks) {
    const int cu = ks * 32 + lhi * 8;
    bf16x8 a[4];
#pragma unroll
    for (int nf = 0; nf < 4; ++nf) {
      int rn = nf * 16 + l16;
      a[nf] = *(const bf16x8*)&sO[rn * 64 + (cu ^ ((rn & 7) * 8))];
    }
#pragma unroll
    for (int cf = 0; cf < 4; ++cf) {
      int rw = w * 64 + cf * 16 + l16;
      bf16x8 bb = *(const bf16x8*)&sWo[rw * 64 + (cu ^ ((rw & 7) * 8))];
#pragma unroll
      for (int nf = 0; nf < 4; ++nf)
        acc[nf][cf] = __builtin_amdgcn_mfma_f32_16x16x32_bf16(a[nf], bb, acc[nf][cf], 0, 0, 0);
    }
  }

  const float gv = *gamma_p;
#pragma unroll
  for (int nf = 0; nf < 4; ++nf) {
    const int n = nt * 64 + nf * 16 + lhi * 4;
#pragma unroll
    for (int cf = 0; cf < 4; ++cf) {
      const int co = ct * 256 + w * 64 + cf * 16 + l16;
      const size_t off = ((size_t)b * CHN + co) * NPOS + n;
      float4 xv = *(const float4*)(x + off);
      float4 rr;
      rr.x = fmaf(gv, acc[nf][cf][0], xv.x);
      rr.y = fmaf(gv, acc[nf][cf][1], xv.y);
      rr.z = fmaf(gv, acc[nf][cf][2], xv.z);
      rr.w = fmaf(gv, acc[nf][cf][3], xv.w);
      *(float4*)(outp + off) = rr;
    }
  }
}

// ---------------------------------------------------------------------------
extern "C" void kernel_launch(void* const* d_in, const int* in_sizes, int n_in,
                              void* d_out, int out_size, void* d_ws, size_t ws_size,
                              hipStream_t stream)
{
  const float* x     = (const float*)d_in[0];
  const float* Wt    = (const float*)d_in[1];
  const float* Wp    = (const float*)d_in[2];
  const float* Wg    = (const float*)d_in[3];
  const float* Wo    = (const float*)d_in[4];
  const float* gamma = (const float*)d_in[5];
  float* out = (float*)d_out;
  float* ws  = (float*)d_ws;

  unsigned short* obf = (unsigned short*)(ws + OFF_O);
  unsigned short* thT = (unsigned short*)(ws + OFF_THT);
  unsigned short* phT = (unsigned short*)(ws + OFF_PHT);
  unsigned short* gbf = (unsigned short*)(ws + OFF_GB);
  unsigned short* wbf = (unsigned short*)(ws + OFF_WBF);
  unsigned short* wob = (unsigned short*)(ws + OFF_WOB);

  prep_w_kernel<<<dim3(512), 256, 0, stream>>>(Wt, Wp, Wg, Wo, wbf, wob);
  qkv_fused_kernel<<<dim3(32, 16), 256, 0, stream>>>(x, wbf, thT, phT, gbf);
  attn_kernel<<<dim3(64, 16), 256, 0, stream>>>(thT, phT, gbf, obf);
  outconv_mfma_kernel<<<dim3(64, 2, 16), 256, 0, stream>>>(x, wob, obf, gamma, out);
}

// Round 7
// 141.470 us; speedup vs baseline: 1.3494x; 1.1480x over previous
//
#include <hip/hip_runtime.h>

#define CHN 512
#define CKD 64
#define NPOS 4096
#define MPOS 1024

typedef __attribute__((ext_vector_type(8))) short bf16x8;
typedef __attribute__((ext_vector_type(4))) float f32x4;
typedef __attribute__((ext_vector_type(8))) unsigned short u16x8;

// workspace offsets (float units)
static constexpr size_t OFF_O   = 0;          // bf16 o [16][4096][64] (n-major, ck-minor)
static constexpr size_t OFF_THT = 4194304;    // bf16 thetaT [16][4096][64]
static constexpr size_t OFF_PHT = 6291456;    // bf16 phiT   [16][1024][64]
static constexpr size_t OFF_GB  = 6815744;    // bf16 g      [16][64][1024]
static constexpr size_t OFF_WBF = 7340032;    // bf16 W[3][64][512] (k-minor, natural)
static constexpr size_t OFF_WOB = 7389184;    // bf16 Wo [512][64] (k-minor, natural)

__device__ __forceinline__ unsigned short f2bf(float f) {
  union { float f; unsigned int u; } v; v.f = f;
  unsigned int r = v.u + 0x7FFFu + ((v.u >> 16) & 1u);
  return (unsigned short)(r >> 16);
}

__device__ __forceinline__ void gl2lds16(const void* g, void* l) {
  __builtin_amdgcn_global_load_lds(
      (const __attribute__((address_space(1))) unsigned int*)g,
      (__attribute__((address_space(3))) unsigned int*)l, 16, 0, 0);
}

// ---------------------------------------------------------------------------
// K0: weight prep. (unchanged)
// ---------------------------------------------------------------------------
__global__ __launch_bounds__(256) void prep_w_kernel(
    const float* __restrict__ Wt, const float* __restrict__ Wp,
    const float* __restrict__ Wg, const float* __restrict__ Wo,
    unsigned short* __restrict__ wbf, unsigned short* __restrict__ wobf)
{
  int id = blockIdx.x * 256 + threadIdx.x;   // 0..131071
  if (id < 98304) {
    int mat = id >> 15, r = id & 32767;
    const float* W = (mat == 0) ? Wt : (mat == 1) ? Wp : Wg;
    wbf[id] = f2bf(W[r]);
  } else {
    int j = id - 98304;                      // 0..32767
    wobf[j] = f2bf(Wo[j]);
  }
}

// ---------------------------------------------------------------------------
// K1: FUSED transpose + qkv GEMM via MFMA. (unchanged from round 6)
// ---------------------------------------------------------------------------
__global__ __launch_bounds__(256) void qkv_fused_kernel(
    const float* __restrict__ x,             // [b][512][4096] fp32
    const unsigned short* __restrict__ wbf,  // [3][64][512]
    unsigned short* __restrict__ thT, unsigned short* __restrict__ phT,
    unsigned short* __restrict__ gbf)
{
  __shared__ unsigned short sXb[64 * 132];   // [c][n] bf16, +4 pad
  __shared__ unsigned short sW[3 * 64 * 64]; // [mat][ck][c] rows 128B, swizzled

  const int bx = blockIdx.x;
  const int b  = blockIdx.y;
  const int t  = threadIdx.x;
  const int w   = t >> 6;
  const int l   = t & 63;
  const int l16 = l & 15;
  const int lhi = l >> 4;
  const int n0  = bx * 128;

  const float* xb = x + (size_t)b * CHN * NPOS + n0;

  f32x4 acc[3][2][4];
#pragma unroll
  for (int m = 0; m < 3; ++m)
#pragma unroll
    for (int nf = 0; nf < 2; ++nf)
#pragma unroll
      for (int ckf = 0; ckf < 4; ++ckf) acc[m][nf][ckf] = (f32x4){0.f, 0.f, 0.f, 0.f};

  for (int c0 = 0; c0 < CHN; c0 += 64) {
    if (c0) __syncthreads();                 // previous chunk readers done
#pragma unroll
    for (int i = 0; i < 8; ++i) {
      int row  = i * 8 + (t >> 5);           // 0..63
      int col4 = t & 31;                     // float4 index along n
      float4 v = *(const float4*)(xb + (size_t)(c0 + row) * NPOS + col4 * 4);
      ushort4 u;
      u.x = f2bf(v.x); u.y = f2bf(v.y); u.z = f2bf(v.z); u.w = f2bf(v.w);
      *(ushort4*)&sXb[row * 132 + col4 * 4] = u;
    }
#pragma unroll
    for (int mi = 0; mi < 6; ++mi) {
      int mat = mi >> 1;
      int row = ((mi & 1) * 4 + w) * 8 + (l >> 3);   // 0..63
      int sbyte = (l & 7) * 16;
      const char* g = (const char*)wbf +
          ((((size_t)mat * 64 + row) * CHN + c0) << 1) + (sbyte ^ ((row & 7) << 4));
      gl2lds16(g, (char*)sW + mi * 4096 + w * 1024);
    }
    __syncthreads();

#pragma unroll
    for (int ks = 0; ks < 2; ++ks) {
      const int cu = ks * 32 + lhi * 8;      // channel base of this k-slice
      bf16x8 a[2];
#pragma unroll
      for (int nf = 0; nf < 2; ++nf) {
        const int rn = 16 * w + 64 * nf + l16;
        bf16x8 av;
#pragma unroll
        for (int e = 0; e < 8; ++e)
          av[e] = (short)sXb[(cu + e) * 132 + rn];
        a[nf] = av;
      }
#pragma unroll
      for (int m = 0; m < 3; ++m)
#pragma unroll
        for (int ckf = 0; ckf < 4; ++ckf) {
          int rw = ckf * 16 + l16;
          bf16x8 bb = *(const bf16x8*)&sW[m * 4096 + rw * 64 + ((ks * 32 + lhi * 8) ^ ((rw & 7) * 8))];
          acc[m][0][ckf] = __builtin_amdgcn_mfma_f32_16x16x32_bf16(a[0], bb, acc[m][0][ckf], 0, 0, 0);
          acc[m][1][ckf] = __builtin_amdgcn_mfma_f32_16x16x32_bf16(a[1], bb, acc[m][1][ckf], 0, 0, 0);
        }
    }
  }

  // epilogue: theta full-res [n][ck] bf16
  unsigned short* th = thT + (size_t)b * NPOS * 64;
#pragma unroll
  for (int nf = 0; nf < 2; ++nf)
#pragma unroll
    for (int r = 0; r < 4; ++r) {
      int n = n0 + 16 * w + 64 * nf + lhi * 4 + r;
#pragma unroll
      for (int ckf = 0; ckf < 4; ++ckf)
        th[(size_t)n * 64 + ckf * 16 + l16] = f2bf(acc[0][nf][ckf][r]);
    }

  // phi/g: 2x2 maxpool in-register. pooled row = bx, col j = 8w + lhi*2 + pr.
  unsigned short* ph = phT + (size_t)b * MPOS * 64;
  unsigned short* gb = gbf + (size_t)b * CKD * MPOS;
#pragma unroll
  for (int pr = 0; pr < 2; ++pr) {
    int mcol = bx * 32 + 8 * w + lhi * 2 + pr;
#pragma unroll
    for (int ckf = 0; ckf < 4; ++ckf) {
      int ck = ckf * 16 + l16;
      float vp = fmaxf(fmaxf(acc[1][0][ckf][2 * pr], acc[1][0][ckf][2 * pr + 1]),
                       fmaxf(acc[1][1][ckf][2 * pr], acc[1][1][ckf][2 * pr + 1]));
      float vg = fmaxf(fmaxf(acc[2][0][ckf][2 * pr], acc[2][0][ckf][2 * pr + 1]),
                       fmaxf(acc[2][1][ckf][2 * pr], acc[2][1][ckf][2 * pr + 1]));
      ph[(size_t)mcol * 64 + ck] = f2bf(vp);
      gb[(size_t)ck * MPOS + mcol] = f2bf(vg);
    }
  }
}

// ---------------------------------------------------------------------------
// K2: fused flash attention. (unchanged from round 6)
// ---------------------------------------------------------------------------
__global__ __launch_bounds__(256) void attn_kernel(
    const unsigned short* __restrict__ thT,  // [b][4096][64]
    const unsigned short* __restrict__ phT,  // [b][1024][64]
    const unsigned short* __restrict__ gbf,  // [b][64][1024]
    unsigned short* __restrict__ obf)        // [b][4096][64] bf16
{
  __shared__ unsigned short sTh[64 * 64];
  __shared__ unsigned short sPhi[64 * 64];
  __shared__ unsigned short sG[64 * 64];
  __shared__ unsigned short sP[64 * 64];

  const int qt = blockIdx.x;
  const int b  = blockIdx.y;
  const int t  = threadIdx.x;
  const int w   = t >> 6;
  const int l   = t & 63;
  const int l16 = l & 15;
  const int lhi = l >> 4;

  {
    const unsigned short* src = thT + ((size_t)b * NPOS + (size_t)qt * 64) * 64;
#pragma unroll
    for (int c = t; c < 512; c += 256) {
      int row = c >> 3, c8 = c & 7;
      *(f32x4*)&sTh[row * 64 + ((c8 * 8) ^ ((row & 7) * 8))] =
          *(const f32x4*)(src + row * 64 + c8 * 8);
    }
  }

  f32x4 oacc[4];
  float m_run[4], l_run[4];
#pragma unroll
  for (int i = 0; i < 4; ++i) {
    oacc[i] = (f32x4){0.f, 0.f, 0.f, 0.f};
    m_run[i] = -1e30f; l_run[i] = 0.f;
  }

  const unsigned short* phb = phT + (size_t)b * MPOS * 64;
  const unsigned short* gb  = gbf + (size_t)b * CKD * MPOS;

  for (int mt = 0; mt < 16; ++mt) {
    __syncthreads();
#pragma unroll
    for (int c = t; c < 512; c += 256) {
      int row = c >> 3, c8 = c & 7;
      *(f32x4*)&sPhi[row * 64 + ((c8 * 8) ^ ((row & 7) * 8))] =
          *(const f32x4*)(phb + (size_t)(mt * 64 + row) * 64 + c8 * 8);
    }
#pragma unroll
    for (int c = t; c < 512; c += 256) {
      int row = c >> 3, c8 = c & 7;
      *(f32x4*)&sG[row * 64 + ((c8 * 8) ^ ((row & 7) * 8))] =
          *(const f32x4*)(gb + (size_t)row * MPOS + mt * 64 + c8 * 8);
    }
    __syncthreads();

    f32x4 sacc[4];
#pragma unroll
    for (int mf = 0; mf < 4; ++mf) sacc[mf] = (f32x4){0.f, 0.f, 0.f, 0.f};
#pragma unroll
    for (int ks = 0; ks < 2; ++ks) {
      const int q  = 16 * w + l16;
      const int ob = lhi * 8 + 32 * ks;
      bf16x8 a = *(const bf16x8*)&sTh[q * 64 + (ob ^ ((q & 7) * 8))];
#pragma unroll
      for (int mf = 0; mf < 4; ++mf) {
        const int m = l16 + 16 * mf;
        bf16x8 bb = *(const bf16x8*)&sPhi[m * 64 + (ob ^ ((m & 7) * 8))];
        sacc[mf] = __builtin_amdgcn_mfma_f32_16x16x32_bf16(a, bb, sacc[mf], 0, 0, 0);
      }
    }

    float sc[4];
#pragma unroll
    for (int r = 0; r < 4; ++r) {
      float mx = fmaxf(fmaxf(sacc[0][r], sacc[1][r]), fmaxf(sacc[2][r], sacc[3][r]));
      mx = fmaxf(mx, __shfl_xor(mx, 1, 64));
      mx = fmaxf(mx, __shfl_xor(mx, 2, 64));
      mx = fmaxf(mx, __shfl_xor(mx, 4, 64));
      mx = fmaxf(mx, __shfl_xor(mx, 8, 64));
      float mnew = fmaxf(m_run[r], mx);
      sc[r] = __expf(m_run[r] - mnew);
      m_run[r] = mnew;
      float rs = 0.f;
#pragma unroll
      for (int mf = 0; mf < 4; ++mf) {
        float p = __expf(sacc[mf][r] - mnew);
        sacc[mf][r] = p;
        rs += p;
      }
      rs += __shfl_xor(rs, 1, 64);
      rs += __shfl_xor(rs, 2, 64);
      rs += __shfl_xor(rs, 4, 64);
      rs += __shfl_xor(rs, 8, 64);
      l_run[r] = l_run[r] * sc[r] + rs;
    }

#pragma unroll
    for (int r = 0; r < 4; ++r) {
      const int qq = 16 * w + lhi * 4 + r;
      const int swz = (qq & 7) * 8;
#pragma unroll
      for (int mf = 0; mf < 4; ++mf) {
        const int m = l16 + 16 * mf;
        sP[qq * 64 + ((m & 0x38) ^ swz) + (m & 7)] = f2bf(sacc[mf][r]);
      }
    }

#pragma unroll
    for (int ckf = 0; ckf < 4; ++ckf)
#pragma unroll
      for (int r = 0; r < 4; ++r) oacc[ckf][r] *= sc[r];

#pragma unroll
    for (int ks = 0; ks < 2; ++ks) {
      const int q  = 16 * w + l16;
      const int ob = lhi * 8 + 32 * ks;
      bf16x8 a = *(const bf16x8*)&sP[q * 64 + (ob ^ ((q & 7) * 8))];
#pragma unroll
      for (int ckf = 0; ckf < 4; ++ckf) {
        const int ck = l16 + 16 * ckf;
        bf16x8 bb = *(const bf16x8*)&sG[ck * 64 + (ob ^ ((ck & 7) * 8))];
        oacc[ckf] = __builtin_amdgcn_mfma_f32_16x16x32_bf16(a, bb, oacc[ckf], 0, 0, 0);
      }
    }
  }

  float inv[4];
#pragma unroll
  for (int r = 0; r < 4; ++r) inv[r] = 1.0f / l_run[r];

  unsigned short* ob = obf + (size_t)b * NPOS * 64;
#pragma unroll
  for (int r = 0; r < 4; ++r) {
    int n = qt * 64 + 16 * w + lhi * 4 + r;
#pragma unroll
    for (int ckf = 0; ckf < 4; ++ckf)
      ob[(size_t)n * 64 + ckf * 16 + l16] = f2bf(oacc[ckf][r] * inv[r]);
  }
}

// ---------------------------------------------------------------------------
// K3: out = x + gamma * (Wo @ o) via bf16 MFMA.
// RETILED: 256 n x 64 co per block, grid (16 nt, 8 ct, 16 b).
// x prefetched into registers BEFORE the barrier so the x-read stream
// overlaps the o/Wo LDS staging; 1KB contiguous per x/out row per block.
// ---------------------------------------------------------------------------
__global__ __launch_bounds__(256) void outconv_mfma_kernel(
    const float* __restrict__ x,
    const unsigned short* __restrict__ wobf,  // [512][64] bf16 k-minor
    const unsigned short* __restrict__ obf,   // [b][4096][64] bf16
    const float* __restrict__ gamma_p, float* __restrict__ outp)
{
  __shared__ unsigned short sO[256 * 64];     // [n][ck] rows 128B, swizzled
  __shared__ unsigned short sWo[64 * 64];     // [co][ck] rows 128B, swizzled

  const int nt = blockIdx.x;                  // 16 tiles of 256 n
  const int ct = blockIdx.y;                  // 8 tiles of 64 co
  const int b  = blockIdx.z;
  const int t  = threadIdx.x;
  const int w   = t >> 6;
  const int l   = t & 63;
  const int l16 = l & 15;
  const int lhi = l >> 4;

  // stage o tile: 256 rows x 128B = 2048 chunks of 16B
#pragma unroll
  for (int i = 0; i < 8; ++i) {
    int cidx = i * 256 + t;                   // = i*256 + w*64 + l
    int row = cidx >> 3, sub = cidx & 7;
    const char* g = (const char*)obf +
        ((((size_t)b * NPOS + nt * 256 + row) * 64) << 1) + ((sub * 16) ^ ((row & 7) << 4));
    gl2lds16(g, (char*)sO + (i * 256 + w * 64) * 16);
  }
  // stage Wo tile: 64 rows x 128B = 512 chunks of 16B
#pragma unroll
  for (int i = 0; i < 2; ++i) {
    int cidx = i * 256 + t;
    int row = cidx >> 3, sub = cidx & 7;      // row 0..63
    const char* g = (const char*)wobf +
        ((((size_t)(ct * 64 + row)) * 64) << 1) + ((sub * 16) ^ ((row & 7) << 4));
    gl2lds16(g, (char*)sWo + (i * 256 + w * 64) * 16);
  }

  // prefetch x into registers (overlaps staging; barrier drains both)
  const float gv = *gamma_p;
  float4 xv[4][4];
#pragma unroll
  for (int nf = 0; nf < 4; ++nf) {
    const int n = nt * 256 + w * 64 + nf * 16 + lhi * 4;
#pragma unroll
    for (int cf = 0; cf < 4; ++cf) {
      const int co = ct * 64 + cf * 16 + l16;
      xv[nf][cf] = *(const float4*)(x + ((size_t)b * CHN + co) * NPOS + n);
    }
  }
  __syncthreads();

  f32x4 acc[4][4];                            // [nf][cf]
#pragma unroll
  for (int nf = 0; nf < 4; ++nf)
#pragma unroll
    for (int cf = 0; cf < 4; ++cf) acc[nf][cf] = (f32x4){0.f, 0.f, 0.f, 0.f};

#pragma unroll
  for (int ks = 0; ks < 2; ++ks) {
    const int cu = ks * 32 + lhi * 8;
    bf16x8 a[4];
#pragma unroll
    for (int nf = 0; nf < 4; ++nf) {
      int rn = w * 64 + nf * 16 + l16;
      a[nf] = *(const bf16x8*)&sO[rn * 64 + (cu ^ ((rn & 7) * 8))];
    }
#pragma unroll
    for (int cf = 0; cf < 4; ++cf) {
      int rw = cf * 16 + l16;
      bf16x8 bb = *(const bf16x8*)&sWo[rw * 64 + (cu ^ ((rw & 7) * 8))];
#pragma unroll
      for (int nf = 0; nf < 4; ++nf)
        acc[nf][cf] = __builtin_amdgcn_mfma_f32_16x16x32_bf16(a[nf], bb, acc[nf][cf], 0, 0, 0);
    }
  }

#pragma unroll
  for (int nf = 0; nf < 4; ++nf) {
    const int n = nt * 256 + w * 64 + nf * 16 + lhi * 4;
#pragma unroll
    for (int cf = 0; cf < 4; ++cf) {
      const int co = ct * 64 + cf * 16 + l16;
      const size_t off = ((size_t)b * CHN + co) * NPOS + n;
      float4 rr;
      rr.x = fmaf(gv, acc[nf][cf][0], xv[nf][cf].x);
      rr.y = fmaf(gv, acc[nf][cf][1], xv[nf][cf].y);
      rr.z = fmaf(gv, acc[nf][cf][2], xv[nf][cf].z);
      rr.w = fmaf(gv, acc[nf][cf][3], xv[nf][cf].w);
      *(float4*)(outp + off) = rr;
    }
  }
}

// ---------------------------------------------------------------------------
extern "C" void kernel_launch(void* const* d_in, const int* in_sizes, int n_in,
                              void* d_out, int out_size, void* d_ws, size_t ws_size,
                              hipStream_t stream)
{
  const float* x     = (const float*)d_in[0];
  const float* Wt    = (const float*)d_in[1];
  const float* Wp    = (const float*)d_in[2];
  const float* Wg    = (const float*)d_in[3];
  const float* Wo    = (const float*)d_in[4];
  const float* gamma = (const float*)d_in[5];
  float* out = (float*)d_out;
  float* ws  = (float*)d_ws;

  unsigned short* obf = (unsigned short*)(ws + OFF_O);
  unsigned short* thT = (unsigned short*)(ws + OFF_THT);
  unsigned short* phT = (unsigned short*)(ws + OFF_PHT);
  unsigned short* gbf = (unsigned short*)(ws + OFF_GB);
  unsigned short* wbf = (unsigned short*)(ws + OFF_WBF);
  unsigned short* wob = (unsigned short*)(ws + OFF_WOB);

  prep_w_kernel<<<dim3(512), 256, 0, stream>>>(Wt, Wp, Wg, Wo, wbf, wob);
  qkv_fused_kernel<<<dim3(32, 16), 256, 0, stream>>>(x, wbf, thT, phT, gbf);
  attn_kernel<<<dim3(64, 16), 256, 0, stream>>>(thT, phT, gbf, obf);
  outconv_mfma_kernel<<<dim3(16, 8, 16), 256, 0, stream>>>(x, wob, obf, gamma, out);
}